// Round 13
// baseline (244.387 us; speedup 1.0000x reference)
//
#include <hip/hip_runtime.h>
#include <math.h>

#define N_NODES 50000
#define N_EDGES 800000
#define F_IN 128
#define HIDDEN 256
#define N_CLASSES 40

#define CHUNK 256
#define NCHUNK ((N_NODES + CHUNK - 1) / CHUNK)  // 196

typedef __attribute__((ext_vector_type(8))) short bf16x8;
typedef __attribute__((ext_vector_type(4))) float f32x4;
typedef __attribute__((ext_vector_type(8))) unsigned short u16x8;

// ---------------- bf16 helpers ----------------

__device__ __forceinline__ float bf2f(unsigned short u) {
    unsigned int t = ((unsigned int)u) << 16;
    float f;
    __builtin_memcpy(&f, &t, 4);
    return f;
}

__device__ __forceinline__ unsigned short f2bf(float f) {
    unsigned int t;
    __builtin_memcpy(&t, &f, 4);
    unsigned int r = (t + 0x7fffu + ((t >> 16) & 1u)) >> 16;  // RNE
    return (unsigned short)r;
}

// ---------------- CSR build ----------------

__global__ void zero_counts(int* __restrict__ counts) {
    int i = blockIdx.x * blockDim.x + threadIdx.x;
    if (i < N_NODES) counts[i] = 0;
}

// edge_index arrives as int32 (JAX x64-disabled downgrades int64)
__global__ void count_kernel(const int* __restrict__ dst, int* __restrict__ counts) {
    int e = blockIdx.x * blockDim.x + threadIdx.x;
    if (e < N_EDGES) {
        int d = dst[e];
        d = (d < 0) ? 0 : (d >= N_NODES ? N_NODES - 1 : d);
        atomicAdd(&counts[d], 1);
    }
}

__global__ __launch_bounds__(256) void scan_partials(const int* __restrict__ counts,
                                                     int* __restrict__ bsum) {
    __shared__ int red[4];
    int b = blockIdx.x;
    int i = b * CHUNK + threadIdx.x;
    int v = (i < N_NODES) ? counts[i] : 0;
    for (int off = 32; off > 0; off >>= 1) v += __shfl_down(v, off, 64);
    int wave = threadIdx.x >> 6;
    int lane = threadIdx.x & 63;
    if (lane == 0) red[wave] = v;
    __syncthreads();
    if (threadIdx.x == 0) bsum[b] = red[0] + red[1] + red[2] + red[3];
}

__global__ __launch_bounds__(256) void scan_bsums(int* __restrict__ bsum,
                                                  int* __restrict__ boff) {
    __shared__ int s[256];
    int tid = threadIdx.x;
    int v = (tid < NCHUNK) ? bsum[tid] : 0;
    s[tid] = v;
    __syncthreads();
    for (int off = 1; off < 256; off <<= 1) {
        int t = (tid >= off) ? s[tid - off] : 0;
        __syncthreads();
        s[tid] += t;
        __syncthreads();
    }
    if (tid < NCHUNK) boff[tid] = s[tid] - v;
    if (tid == NCHUNK - 1) boff[NCHUNK] = s[tid];
}

__global__ __launch_bounds__(256) void scan_apply(const int* __restrict__ counts,
                                                  const int* __restrict__ boff,
                                                  int* __restrict__ row_off,
                                                  int* __restrict__ cursor,
                                                  float* __restrict__ inv_deg) {
    __shared__ int s[256];
    int b = blockIdx.x;
    int tid = threadIdx.x;
    int i = b * CHUNK + tid;
    int v = (i < N_NODES) ? counts[i] : 0;
    s[tid] = v;
    __syncthreads();
    for (int off = 1; off < 256; off <<= 1) {
        int t = (tid >= off) ? s[tid - off] : 0;
        __syncthreads();
        s[tid] += t;
        __syncthreads();
    }
    if (i < N_NODES) {
        int excl = boff[b] + s[tid] - v;
        row_off[i] = excl;
        cursor[i] = excl;
        inv_deg[i] = 1.0f / fmaxf((float)v, 1.0f);
        if (i == N_NODES - 1) row_off[N_NODES] = excl + v;
    }
}

__global__ void fill_kernel(const int* __restrict__ ei, int* __restrict__ cursor,
                            int* __restrict__ csr_src) {
    int e = blockIdx.x * blockDim.x + threadIdx.x;
    if (e < N_EDGES) {
        int s = ei[e];
        int d = ei[N_EDGES + e];
        s = (s < 0) ? 0 : (s >= N_NODES ? N_NODES - 1 : s);
        d = (d < 0) ? 0 : (d >= N_NODES ? N_NODES - 1 : d);
        int pos = atomicAdd(&cursor[d], 1);
        if (pos >= 0 && pos < N_EDGES) csr_src[pos] = s;
    }
}

// ---------------- x -> bf16 conversion ----------------

__global__ void conv_x16(const float* __restrict__ x, unsigned short* __restrict__ x16) {
    int i = blockIdx.x * blockDim.x + threadIdx.x;  // 4 elems/thread
    if (i < N_NODES * F_IN / 4) {
        float4 v = reinterpret_cast<const float4*>(x)[i];
        ushort4 o;
        o.x = f2bf(v.x); o.y = f2bf(v.y); o.z = f2bf(v.z); o.w = f2bf(v.w);
        reinterpret_cast<ushort4*>(x16)[i] = o;
    }
}

// ---------------- weight packs ----------------

__global__ void pack_w1(const float* __restrict__ W1l, const float* __restrict__ W1r,
                        unsigned short* __restrict__ Wpk) {
    int n = blockIdx.x;
    int k = threadIdx.x;
    float v = (k < F_IN) ? W1l[(size_t)k * HIDDEN + n] : W1r[(size_t)(k - F_IN) * HIDDEN + n];
    Wpk[(size_t)n * 256 + k] = f2bf(v);
}

// Wpk2n[n][k] bf16, n in [0,128): n<64 -> W2l col n (0 if n>=40); n>=64 -> W2r col n-64 (0 if >=40)
__global__ void pack_w2n(const float* __restrict__ W2l, const float* __restrict__ W2r,
                         unsigned short* __restrict__ Wpk2n) {
    int n = blockIdx.x;   // 0..127
    int k = threadIdx.x;  // 0..255
    float v = 0.f;
    if (n < 64) {
        if (n < N_CLASSES) v = W2l[(size_t)k * N_CLASSES + n];
    } else {
        int m = n - 64;
        if (m < N_CLASSES) v = W2r[(size_t)k * N_CLASSES + m];
    }
    Wpk2n[(size_t)n * 256 + k] = f2bf(v);
}

// ---------------- layer 1: quarter-per-node gather + MFMA + relu -> h16 ----------------
// 256 threads (4 waves), 16 nodes/block. Quarter-wave OWNS one node (j = tid>>4):
// all 16 nodes gather in parallel; unroll 8 = 8x16B loads in flight per lane; no shuffles.

#define AS1_STRIDE 264

__global__ __launch_bounds__(256) void gemm1_fused(
    const unsigned short* __restrict__ x16, const int* __restrict__ row_off,
    const int* __restrict__ csr_src, const float* __restrict__ inv_deg,
    const unsigned short* __restrict__ Wpk, const float* __restrict__ b1,
    unsigned short* __restrict__ h16) {
    __shared__ __align__(16) unsigned short As[16][AS1_STRIDE];
    int n0 = blockIdx.x * 16;
    int tid = threadIdx.x;
    int wave = tid >> 6;
    int lane = tid & 63;
    int j = tid >> 4;    // node 0..15, one quarter-wave each
    int fl = tid & 15;   // feature lane: 8 bf16 at fl*8

    {
        int n = n0 + j;
        int e0 = row_off[n], e1 = row_off[n + 1];
        int deg = e1 - e0;
        float a[8] = {0.f, 0.f, 0.f, 0.f, 0.f, 0.f, 0.f, 0.f};
        int it = 0;
        for (; it + 7 < deg; it += 8) {  // 8 rows in flight per lane
            int s0 = csr_src[e0 + it + 0];
            int s1 = csr_src[e0 + it + 1];
            int s2 = csr_src[e0 + it + 2];
            int s3 = csr_src[e0 + it + 3];
            int s4 = csr_src[e0 + it + 4];
            int s5 = csr_src[e0 + it + 5];
            int s6 = csr_src[e0 + it + 6];
            int s7 = csr_src[e0 + it + 7];
            u16x8 v0 = *reinterpret_cast<const u16x8*>(x16 + (size_t)s0 * F_IN + fl * 8);
            u16x8 v1 = *reinterpret_cast<const u16x8*>(x16 + (size_t)s1 * F_IN + fl * 8);
            u16x8 v2 = *reinterpret_cast<const u16x8*>(x16 + (size_t)s2 * F_IN + fl * 8);
            u16x8 v3 = *reinterpret_cast<const u16x8*>(x16 + (size_t)s3 * F_IN + fl * 8);
            u16x8 v4 = *reinterpret_cast<const u16x8*>(x16 + (size_t)s4 * F_IN + fl * 8);
            u16x8 v5 = *reinterpret_cast<const u16x8*>(x16 + (size_t)s5 * F_IN + fl * 8);
            u16x8 v6 = *reinterpret_cast<const u16x8*>(x16 + (size_t)s6 * F_IN + fl * 8);
            u16x8 v7 = *reinterpret_cast<const u16x8*>(x16 + (size_t)s7 * F_IN + fl * 8);
#pragma unroll
            for (int i = 0; i < 8; ++i)
                a[i] += ((bf2f(v0[i]) + bf2f(v1[i])) + (bf2f(v2[i]) + bf2f(v3[i]))) +
                        ((bf2f(v4[i]) + bf2f(v5[i])) + (bf2f(v6[i]) + bf2f(v7[i])));
        }
        if (it + 3 < deg) {  // 4 rows
            int s0 = csr_src[e0 + it + 0];
            int s1 = csr_src[e0 + it + 1];
            int s2 = csr_src[e0 + it + 2];
            int s3 = csr_src[e0 + it + 3];
            u16x8 v0 = *reinterpret_cast<const u16x8*>(x16 + (size_t)s0 * F_IN + fl * 8);
            u16x8 v1 = *reinterpret_cast<const u16x8*>(x16 + (size_t)s1 * F_IN + fl * 8);
            u16x8 v2 = *reinterpret_cast<const u16x8*>(x16 + (size_t)s2 * F_IN + fl * 8);
            u16x8 v3 = *reinterpret_cast<const u16x8*>(x16 + (size_t)s3 * F_IN + fl * 8);
#pragma unroll
            for (int i = 0; i < 8; ++i)
                a[i] += (bf2f(v0[i]) + bf2f(v1[i])) + (bf2f(v2[i]) + bf2f(v3[i]));
            it += 4;
        }
        for (; it < deg; ++it) {  // up to 3 singles
            int s = csr_src[e0 + it];
            u16x8 v = *reinterpret_cast<const u16x8*>(x16 + (size_t)s * F_IN + fl * 8);
#pragma unroll
            for (int i = 0; i < 8; ++i) a[i] += bf2f(v[i]);
        }
        float id = inv_deg[n];
        u16x8 m;
#pragma unroll
        for (int i = 0; i < 8; ++i) m[i] = f2bf(a[i] * id);
        *reinterpret_cast<u16x8*>(&As[j][fl * 8]) = m;
        *reinterpret_cast<u16x8*>(&As[j][F_IN + fl * 8]) =
            *reinterpret_cast<const u16x8*>(x16 + (size_t)n * F_IN + fl * 8);
    }
    __syncthreads();

    // ---- MFMA phase (m89-verified layout, unchanged) ----
    int mrow = lane & 15;
    int kg = lane >> 4;
    f32x4 acc0 = {0.f, 0.f, 0.f, 0.f};
    f32x4 acc1 = {0.f, 0.f, 0.f, 0.f};
    f32x4 acc2 = {0.f, 0.f, 0.f, 0.f};
    f32x4 acc3 = {0.f, 0.f, 0.f, 0.f};
    const unsigned short* wp = Wpk + ((size_t)(wave * 4) * 16 + mrow) * 256 + kg * 8;
#pragma unroll
    for (int ks = 0; ks < 8; ++ks) {
        bf16x8 a = *reinterpret_cast<const bf16x8*>(&As[mrow][ks * 32 + kg * 8]);
        bf16x8 b0 = *reinterpret_cast<const bf16x8*>(wp + 0 * 16 * 256 + ks * 32);
        bf16x8 b1f = *reinterpret_cast<const bf16x8*>(wp + 1 * 16 * 256 + ks * 32);
        bf16x8 b2 = *reinterpret_cast<const bf16x8*>(wp + 2 * 16 * 256 + ks * 32);
        bf16x8 b3 = *reinterpret_cast<const bf16x8*>(wp + 3 * 16 * 256 + ks * 32);
        acc0 = __builtin_amdgcn_mfma_f32_16x16x32_bf16(a, b0, acc0, 0, 0, 0);
        acc1 = __builtin_amdgcn_mfma_f32_16x16x32_bf16(a, b1f, acc1, 0, 0, 0);
        acc2 = __builtin_amdgcn_mfma_f32_16x16x32_bf16(a, b2, acc2, 0, 0, 0);
        acc3 = __builtin_amdgcn_mfma_f32_16x16x32_bf16(a, b3, acc3, 0, 0, 0);
    }
    f32x4 accs[4] = {acc0, acc1, acc2, acc3};
#pragma unroll
    for (int i = 0; i < 4; ++i) {
        int n = (wave * 4 + i) * 16 + mrow;
        float bb = b1[n];
#pragma unroll
        for (int r = 0; r < 4; ++r) {
            int row = kg * 4 + r;
            h16[(size_t)(n0 + row) * HIDDEN + n] = f2bf(fmaxf(accs[i][r] + bb, 0.f));
        }
    }
}

// ---------------- proj2: hWl = h@W2l (bf16 [n][64]), hWr = h@W2r + b2 (bf16 [n][48]) ----------

__global__ __launch_bounds__(256) void proj2(
    const unsigned short* __restrict__ h16, const unsigned short* __restrict__ Wpk2n,
    const float* __restrict__ b2, unsigned short* __restrict__ hWl,
    unsigned short* __restrict__ hWr) {
    __shared__ __align__(16) unsigned short As[16][AS1_STRIDE];
    int n0 = blockIdx.x * 16;
    int tid = threadIdx.x;
    int wave = tid >> 6;
    int lane = tid & 63;

#pragma unroll
    for (int itn = 0; itn < 2; ++itn) {
        int u = itn * 256 + tid;
        int row = u >> 5;
        int col = (u & 31) * 8;
        *reinterpret_cast<u16x8*>(&As[row][col]) =
            *reinterpret_cast<const u16x8*>(h16 + (size_t)(n0 + row) * HIDDEN + col);
    }
    __syncthreads();

    int mrow = lane & 15;
    int kg = lane >> 4;
    f32x4 accL = {0.f, 0.f, 0.f, 0.f};
    f32x4 accR = {0.f, 0.f, 0.f, 0.f};
    const unsigned short* wpL = Wpk2n + ((size_t)(wave * 16 + mrow)) * 256 + kg * 8;
    const unsigned short* wpR = Wpk2n + ((size_t)((wave + 4) * 16 + mrow)) * 256 + kg * 8;
#pragma unroll
    for (int ks = 0; ks < 8; ++ks) {
        bf16x8 a = *reinterpret_cast<const bf16x8*>(&As[mrow][ks * 32 + kg * 8]);
        bf16x8 bL = *reinterpret_cast<const bf16x8*>(wpL + ks * 32);
        bf16x8 bR = *reinterpret_cast<const bf16x8*>(wpR + ks * 32);
        accL = __builtin_amdgcn_mfma_f32_16x16x32_bf16(a, bL, accL, 0, 0, 0);
        accR = __builtin_amdgcn_mfma_f32_16x16x32_bf16(a, bR, accR, 0, 0, 0);
    }
    int colL = wave * 16 + mrow;
    int colR = wave * 16 + mrow;
    float bb = (colR < N_CLASSES) ? b2[colR] : 0.f;
#pragma unroll
    for (int r = 0; r < 4; ++r) {
        int row = kg * 4 + r;
        hWl[(size_t)(n0 + row) * 64 + colL] = f2bf(accL[r]);
        if (colR < 48) hWr[(size_t)(n0 + row) * 48 + colR] = f2bf(accR[r] + bb);
    }
}

// ---------------- k2b: quarter-per-node gather of hWl + hWr[dst] + log_softmax ----------------
// 256 threads, 16 nodes/block, no LDS. Quarter-wave owns node j = tid>>4; lane covers 4 cols.
// Unroll 8 = 8x8B loads in flight per lane.

__global__ __launch_bounds__(256) void k2b(
    const unsigned short* __restrict__ hWl, const unsigned short* __restrict__ hWr,
    const int* __restrict__ row_off, const int* __restrict__ csr_src,
    const float* __restrict__ inv_deg, float* __restrict__ out) {
    int n0 = blockIdx.x * 16;
    int tid = threadIdx.x;
    int j = tid >> 4;    // node 0..15
    int fl = tid & 15;   // cols fl*4 .. fl*4+3

    int n = n0 + j;
    int e0 = row_off[n], e1 = row_off[n + 1];
    int deg = e1 - e0;
    float a0 = 0.f, a1 = 0.f, a2 = 0.f, a3 = 0.f;
    int it = 0;
    for (; it + 7 < deg; it += 8) {
        int s0 = csr_src[e0 + it + 0];
        int s1 = csr_src[e0 + it + 1];
        int s2 = csr_src[e0 + it + 2];
        int s3 = csr_src[e0 + it + 3];
        int s4 = csr_src[e0 + it + 4];
        int s5 = csr_src[e0 + it + 5];
        int s6 = csr_src[e0 + it + 6];
        int s7 = csr_src[e0 + it + 7];
        ushort4 v0 = *reinterpret_cast<const ushort4*>(hWl + (size_t)s0 * 64 + fl * 4);
        ushort4 v1 = *reinterpret_cast<const ushort4*>(hWl + (size_t)s1 * 64 + fl * 4);
        ushort4 v2 = *reinterpret_cast<const ushort4*>(hWl + (size_t)s2 * 64 + fl * 4);
        ushort4 v3 = *reinterpret_cast<const ushort4*>(hWl + (size_t)s3 * 64 + fl * 4);
        ushort4 v4 = *reinterpret_cast<const ushort4*>(hWl + (size_t)s4 * 64 + fl * 4);
        ushort4 v5 = *reinterpret_cast<const ushort4*>(hWl + (size_t)s5 * 64 + fl * 4);
        ushort4 v6 = *reinterpret_cast<const ushort4*>(hWl + (size_t)s6 * 64 + fl * 4);
        ushort4 v7 = *reinterpret_cast<const ushort4*>(hWl + (size_t)s7 * 64 + fl * 4);
        a0 += ((bf2f(v0.x) + bf2f(v1.x)) + (bf2f(v2.x) + bf2f(v3.x))) +
              ((bf2f(v4.x) + bf2f(v5.x)) + (bf2f(v6.x) + bf2f(v7.x)));
        a1 += ((bf2f(v0.y) + bf2f(v1.y)) + (bf2f(v2.y) + bf2f(v3.y))) +
              ((bf2f(v4.y) + bf2f(v5.y)) + (bf2f(v6.y) + bf2f(v7.y)));
        a2 += ((bf2f(v0.z) + bf2f(v1.z)) + (bf2f(v2.z) + bf2f(v3.z))) +
              ((bf2f(v4.z) + bf2f(v5.z)) + (bf2f(v6.z) + bf2f(v7.z)));
        a3 += ((bf2f(v0.w) + bf2f(v1.w)) + (bf2f(v2.w) + bf2f(v3.w))) +
              ((bf2f(v4.w) + bf2f(v5.w)) + (bf2f(v6.w) + bf2f(v7.w)));
    }
    if (it + 3 < deg) {
        int s0 = csr_src[e0 + it + 0];
        int s1 = csr_src[e0 + it + 1];
        int s2 = csr_src[e0 + it + 2];
        int s3 = csr_src[e0 + it + 3];
        ushort4 v0 = *reinterpret_cast<const ushort4*>(hWl + (size_t)s0 * 64 + fl * 4);
        ushort4 v1 = *reinterpret_cast<const ushort4*>(hWl + (size_t)s1 * 64 + fl * 4);
        ushort4 v2 = *reinterpret_cast<const ushort4*>(hWl + (size_t)s2 * 64 + fl * 4);
        ushort4 v3 = *reinterpret_cast<const ushort4*>(hWl + (size_t)s3 * 64 + fl * 4);
        a0 += (bf2f(v0.x) + bf2f(v1.x)) + (bf2f(v2.x) + bf2f(v3.x));
        a1 += (bf2f(v0.y) + bf2f(v1.y)) + (bf2f(v2.y) + bf2f(v3.y));
        a2 += (bf2f(v0.z) + bf2f(v1.z)) + (bf2f(v2.z) + bf2f(v3.z));
        a3 += (bf2f(v0.w) + bf2f(v1.w)) + (bf2f(v2.w) + bf2f(v3.w));
        it += 4;
    }
    for (; it < deg; ++it) {
        int s = csr_src[e0 + it];
        ushort4 v = *reinterpret_cast<const ushort4*>(hWl + (size_t)s * 64 + fl * 4);
        a0 += bf2f(v.x); a1 += bf2f(v.y); a2 += bf2f(v.z); a3 += bf2f(v.w);
    }

    float v0 = 0.f, v1 = 0.f, v2 = 0.f, v3 = 0.f;
    bool valid = (fl < 10);  // cols fl*4..fl*4+3 < 40
    if (valid) {
        float id = inv_deg[n];
        ushort4 r = *reinterpret_cast<const ushort4*>(hWr + (size_t)n * 48 + fl * 4);
        v0 = a0 * id + bf2f(r.x);
        v1 = a1 * id + bf2f(r.y);
        v2 = a2 * id + bf2f(r.z);
        v3 = a3 * id + bf2f(r.w);
    }
    float m = valid ? fmaxf(fmaxf(v0, v1), fmaxf(v2, v3)) : -1e30f;
    m = fmaxf(m, __shfl_xor(m, 1));
    m = fmaxf(m, __shfl_xor(m, 2));
    m = fmaxf(m, __shfl_xor(m, 4));
    m = fmaxf(m, __shfl_xor(m, 8));
    float s = valid ? (expf(v0 - m) + expf(v1 - m)) + (expf(v2 - m) + expf(v3 - m)) : 0.f;
    s += __shfl_xor(s, 1);
    s += __shfl_xor(s, 2);
    s += __shfl_xor(s, 4);
    s += __shfl_xor(s, 8);
    float lse = m + logf(s);
    if (valid) {
        float4 o;
        o.x = v0 - lse; o.y = v1 - lse; o.z = v2 - lse; o.w = v3 - lse;
        *reinterpret_cast<float4*>(out + (size_t)n * N_CLASSES + fl * 4) = o;
    }
}

// ---------------- launch ----------------

extern "C" void kernel_launch(void* const* d_in, const int* in_sizes, int n_in,
                              void* d_out, int out_size, void* d_ws, size_t ws_size,
                              hipStream_t stream) {
    const float* x = (const float*)d_in[0];
    const int* ei = (const int*)d_in[1];  // int32 per harness contract
    const float* W1l = (const float*)d_in[2];
    const float* W1r = (const float*)d_in[3];
    const float* b1 = (const float*)d_in[4];
    const float* W2l = (const float*)d_in[5];
    const float* W2r = (const float*)d_in[6];
    const float* b2 = (const float*)d_in[7];
    float* out = (float*)d_out;

    char* p = (char*)d_ws;
    size_t off = 0;
    auto take = [&](size_t bytes) -> void* {
        void* r = p + off;
        off = (off + bytes + 255) & ~(size_t)255;
        return r;
    };
    int* counts = (int*)take(N_NODES * sizeof(int));
    int* row_off = (int*)take((N_NODES + 1) * sizeof(int));
    int* cursor = (int*)take(N_NODES * sizeof(int));
    float* invdeg = (float*)take(N_NODES * sizeof(float));
    int* csr_src = (int*)take(N_EDGES * sizeof(int));
    int* bsum = (int*)take((NCHUNK + 1) * sizeof(int));
    int* boff = (int*)take((NCHUNK + 1) * sizeof(int));
    unsigned short* h16 = (unsigned short*)take((size_t)N_NODES * HIDDEN * sizeof(unsigned short));
    unsigned short* Wpk1 = (unsigned short*)take(256 * 256 * sizeof(unsigned short));
    unsigned short* Wpk2n = (unsigned short*)take(128 * 256 * sizeof(unsigned short));
    unsigned short* x16 = (unsigned short*)take((size_t)N_NODES * F_IN * sizeof(unsigned short));
    // x16 (12.8 MB) is dead after gemm1; hWl (6.4 MB) + hWr (4.8 MB) reuse its space.
    unsigned short* hWl = x16;
    unsigned short* hWr = x16 + (size_t)N_NODES * 64;

    zero_counts<<<(N_NODES + 255) / 256, 256, 0, stream>>>(counts);
    count_kernel<<<(N_EDGES + 255) / 256, 256, 0, stream>>>(ei + N_EDGES, counts);
    scan_partials<<<NCHUNK, 256, 0, stream>>>(counts, bsum);
    scan_bsums<<<1, 256, 0, stream>>>(bsum, boff);
    scan_apply<<<NCHUNK, 256, 0, stream>>>(counts, boff, row_off, cursor, invdeg);
    fill_kernel<<<(N_EDGES + 255) / 256, 256, 0, stream>>>(ei, cursor, csr_src);
    pack_w1<<<256, 256, 0, stream>>>(W1l, W1r, Wpk1);
    pack_w2n<<<128, 256, 0, stream>>>(W2l, W2r, Wpk2n);
    conv_x16<<<(N_NODES * F_IN / 4 + 255) / 256, 256, 0, stream>>>(x, x16);
    gemm1_fused<<<N_NODES / 16, 256, 0, stream>>>(x16, row_off, csr_src, invdeg, Wpk1, b1, h16);
    proj2<<<N_NODES / 16, 256, 0, stream>>>(h16, Wpk2n, b2, hWl, hWr);
    k2b<<<N_NODES / 16, 256, 0, stream>>>(hWl, hWr, row_off, csr_src, invdeg, out);
}

// Round 14
// 234.426 us; speedup vs baseline: 1.0425x; 1.0425x over previous
//
#include <hip/hip_runtime.h>
#include <math.h>

#define N_NODES 50000
#define N_EDGES 800000
#define F_IN 128
#define HIDDEN 256
#define N_CLASSES 40

#define CHUNK 256
#define NCHUNK ((N_NODES + CHUNK - 1) / CHUNK)  // 196

typedef __attribute__((ext_vector_type(8))) short bf16x8;
typedef __attribute__((ext_vector_type(4))) float f32x4;
typedef __attribute__((ext_vector_type(8))) unsigned short u16x8;

// ---------------- bf16 helpers ----------------

__device__ __forceinline__ float bf2f(unsigned short u) {
    unsigned int t = ((unsigned int)u) << 16;
    float f;
    __builtin_memcpy(&f, &t, 4);
    return f;
}

__device__ __forceinline__ unsigned short f2bf(float f) {
    unsigned int t;
    __builtin_memcpy(&t, &f, 4);
    unsigned int r = (t + 0x7fffu + ((t >> 16) & 1u)) >> 16;  // RNE
    return (unsigned short)r;
}

// ---------------- CSR build ----------------

__global__ void zero_counts(int* __restrict__ counts) {
    int i = blockIdx.x * blockDim.x + threadIdx.x;
    if (i < N_NODES) counts[i] = 0;
}

// edge_index arrives as int32 (JAX x64-disabled downgrades int64)
__global__ void count_kernel(const int* __restrict__ dst, int* __restrict__ counts) {
    int e = blockIdx.x * blockDim.x + threadIdx.x;
    if (e < N_EDGES) {
        int d = dst[e];
        d = (d < 0) ? 0 : (d >= N_NODES ? N_NODES - 1 : d);
        atomicAdd(&counts[d], 1);
    }
}

__global__ __launch_bounds__(256) void scan_partials(const int* __restrict__ counts,
                                                     int* __restrict__ bsum) {
    __shared__ int red[4];
    int b = blockIdx.x;
    int i = b * CHUNK + threadIdx.x;
    int v = (i < N_NODES) ? counts[i] : 0;
    for (int off = 32; off > 0; off >>= 1) v += __shfl_down(v, off, 64);
    int wave = threadIdx.x >> 6;
    int lane = threadIdx.x & 63;
    if (lane == 0) red[wave] = v;
    __syncthreads();
    if (threadIdx.x == 0) bsum[b] = red[0] + red[1] + red[2] + red[3];
}

__global__ __launch_bounds__(256) void scan_bsums(int* __restrict__ bsum,
                                                  int* __restrict__ boff) {
    __shared__ int s[256];
    int tid = threadIdx.x;
    int v = (tid < NCHUNK) ? bsum[tid] : 0;
    s[tid] = v;
    __syncthreads();
    for (int off = 1; off < 256; off <<= 1) {
        int t = (tid >= off) ? s[tid - off] : 0;
        __syncthreads();
        s[tid] += t;
        __syncthreads();
    }
    if (tid < NCHUNK) boff[tid] = s[tid] - v;
    if (tid == NCHUNK - 1) boff[NCHUNK] = s[tid];
}

__global__ __launch_bounds__(256) void scan_apply(const int* __restrict__ counts,
                                                  const int* __restrict__ boff,
                                                  int* __restrict__ row_off,
                                                  int* __restrict__ cursor,
                                                  float* __restrict__ inv_deg) {
    __shared__ int s[256];
    int b = blockIdx.x;
    int tid = threadIdx.x;
    int i = b * CHUNK + tid;
    int v = (i < N_NODES) ? counts[i] : 0;
    s[tid] = v;
    __syncthreads();
    for (int off = 1; off < 256; off <<= 1) {
        int t = (tid >= off) ? s[tid - off] : 0;
        __syncthreads();
        s[tid] += t;
        __syncthreads();
    }
    if (i < N_NODES) {
        int excl = boff[b] + s[tid] - v;
        row_off[i] = excl;
        cursor[i] = excl;
        inv_deg[i] = 1.0f / fmaxf((float)v, 1.0f);
        if (i == N_NODES - 1) row_off[N_NODES] = excl + v;
    }
}

__global__ void fill_kernel(const int* __restrict__ ei, int* __restrict__ cursor,
                            int* __restrict__ csr_src) {
    int e = blockIdx.x * blockDim.x + threadIdx.x;
    if (e < N_EDGES) {
        int s = ei[e];
        int d = ei[N_EDGES + e];
        s = (s < 0) ? 0 : (s >= N_NODES ? N_NODES - 1 : s);
        d = (d < 0) ? 0 : (d >= N_NODES ? N_NODES - 1 : d);
        int pos = atomicAdd(&cursor[d], 1);
        if (pos >= 0 && pos < N_EDGES) csr_src[pos] = s;
    }
}

// ---------------- x -> bf16 conversion ----------------

__global__ void conv_x16(const float* __restrict__ x, unsigned short* __restrict__ x16) {
    int i = blockIdx.x * blockDim.x + threadIdx.x;  // 4 elems/thread
    if (i < N_NODES * F_IN / 4) {
        float4 v = reinterpret_cast<const float4*>(x)[i];
        ushort4 o;
        o.x = f2bf(v.x); o.y = f2bf(v.y); o.z = f2bf(v.z); o.w = f2bf(v.w);
        reinterpret_cast<ushort4*>(x16)[i] = o;
    }
}

// ---------------- weight packs ----------------

__global__ void pack_w1(const float* __restrict__ W1l, const float* __restrict__ W1r,
                        unsigned short* __restrict__ Wpk) {
    int n = blockIdx.x;
    int k = threadIdx.x;
    float v = (k < F_IN) ? W1l[(size_t)k * HIDDEN + n] : W1r[(size_t)(k - F_IN) * HIDDEN + n];
    Wpk[(size_t)n * 256 + k] = f2bf(v);
}

// Wpk2n[n][k] bf16, n in [0,128): n<64 -> W2l col n (0 if n>=40); n>=64 -> W2r col n-64 (0 if >=40)
__global__ void pack_w2n(const float* __restrict__ W2l, const float* __restrict__ W2r,
                         unsigned short* __restrict__ Wpk2n) {
    int n = blockIdx.x;   // 0..127
    int k = threadIdx.x;  // 0..255
    float v = 0.f;
    if (n < 64) {
        if (n < N_CLASSES) v = W2l[(size_t)k * N_CLASSES + n];
    } else {
        int m = n - 64;
        if (m < N_CLASSES) v = W2r[(size_t)k * N_CLASSES + m];
    }
    Wpk2n[(size_t)n * 256 + k] = f2bf(v);
}

// ---------------- layer 1: quarter-per-node gather + MFMA + relu -> h16 ----------------
// 256 threads (4 waves), 16 nodes/block. Quarter-wave OWNS one node (j = tid>>4):
// all 16 nodes gather in parallel; unroll 8 = 8x16B loads in flight per lane; no shuffles.

#define AS1_STRIDE 264

__global__ __launch_bounds__(256) void gemm1_fused(
    const unsigned short* __restrict__ x16, const int* __restrict__ row_off,
    const int* __restrict__ csr_src, const float* __restrict__ inv_deg,
    const unsigned short* __restrict__ Wpk, const float* __restrict__ b1,
    unsigned short* __restrict__ h16) {
    __shared__ __align__(16) unsigned short As[16][AS1_STRIDE];
    int n0 = blockIdx.x * 16;
    int tid = threadIdx.x;
    int wave = tid >> 6;
    int lane = tid & 63;
    int j = tid >> 4;    // node 0..15, one quarter-wave each
    int fl = tid & 15;   // feature lane: 8 bf16 at fl*8

    {
        int n = n0 + j;
        int e0 = row_off[n], e1 = row_off[n + 1];
        int deg = e1 - e0;
        float a[8] = {0.f, 0.f, 0.f, 0.f, 0.f, 0.f, 0.f, 0.f};
        int it = 0;
        for (; it + 7 < deg; it += 8) {  // 8 rows in flight per lane
            int s0 = csr_src[e0 + it + 0];
            int s1 = csr_src[e0 + it + 1];
            int s2 = csr_src[e0 + it + 2];
            int s3 = csr_src[e0 + it + 3];
            int s4 = csr_src[e0 + it + 4];
            int s5 = csr_src[e0 + it + 5];
            int s6 = csr_src[e0 + it + 6];
            int s7 = csr_src[e0 + it + 7];
            u16x8 v0 = *reinterpret_cast<const u16x8*>(x16 + (size_t)s0 * F_IN + fl * 8);
            u16x8 v1 = *reinterpret_cast<const u16x8*>(x16 + (size_t)s1 * F_IN + fl * 8);
            u16x8 v2 = *reinterpret_cast<const u16x8*>(x16 + (size_t)s2 * F_IN + fl * 8);
            u16x8 v3 = *reinterpret_cast<const u16x8*>(x16 + (size_t)s3 * F_IN + fl * 8);
            u16x8 v4 = *reinterpret_cast<const u16x8*>(x16 + (size_t)s4 * F_IN + fl * 8);
            u16x8 v5 = *reinterpret_cast<const u16x8*>(x16 + (size_t)s5 * F_IN + fl * 8);
            u16x8 v6 = *reinterpret_cast<const u16x8*>(x16 + (size_t)s6 * F_IN + fl * 8);
            u16x8 v7 = *reinterpret_cast<const u16x8*>(x16 + (size_t)s7 * F_IN + fl * 8);
#pragma unroll
            for (int i = 0; i < 8; ++i)
                a[i] += ((bf2f(v0[i]) + bf2f(v1[i])) + (bf2f(v2[i]) + bf2f(v3[i]))) +
                        ((bf2f(v4[i]) + bf2f(v5[i])) + (bf2f(v6[i]) + bf2f(v7[i])));
        }
        if (it + 3 < deg) {  // 4 rows
            int s0 = csr_src[e0 + it + 0];
            int s1 = csr_src[e0 + it + 1];
            int s2 = csr_src[e0 + it + 2];
            int s3 = csr_src[e0 + it + 3];
            u16x8 v0 = *reinterpret_cast<const u16x8*>(x16 + (size_t)s0 * F_IN + fl * 8);
            u16x8 v1 = *reinterpret_cast<const u16x8*>(x16 + (size_t)s1 * F_IN + fl * 8);
            u16x8 v2 = *reinterpret_cast<const u16x8*>(x16 + (size_t)s2 * F_IN + fl * 8);
            u16x8 v3 = *reinterpret_cast<const u16x8*>(x16 + (size_t)s3 * F_IN + fl * 8);
#pragma unroll
            for (int i = 0; i < 8; ++i)
                a[i] += (bf2f(v0[i]) + bf2f(v1[i])) + (bf2f(v2[i]) + bf2f(v3[i]));
            it += 4;
        }
        for (; it < deg; ++it) {  // up to 3 singles
            int s = csr_src[e0 + it];
            u16x8 v = *reinterpret_cast<const u16x8*>(x16 + (size_t)s * F_IN + fl * 8);
#pragma unroll
            for (int i = 0; i < 8; ++i) a[i] += bf2f(v[i]);
        }
        float id = inv_deg[n];
        u16x8 m;
#pragma unroll
        for (int i = 0; i < 8; ++i) m[i] = f2bf(a[i] * id);
        *reinterpret_cast<u16x8*>(&As[j][fl * 8]) = m;
        *reinterpret_cast<u16x8*>(&As[j][F_IN + fl * 8]) =
            *reinterpret_cast<const u16x8*>(x16 + (size_t)n * F_IN + fl * 8);
    }
    __syncthreads();

    // ---- MFMA phase (m89-verified layout, unchanged) ----
    int mrow = lane & 15;
    int kg = lane >> 4;
    f32x4 acc0 = {0.f, 0.f, 0.f, 0.f};
    f32x4 acc1 = {0.f, 0.f, 0.f, 0.f};
    f32x4 acc2 = {0.f, 0.f, 0.f, 0.f};
    f32x4 acc3 = {0.f, 0.f, 0.f, 0.f};
    const unsigned short* wp = Wpk + ((size_t)(wave * 4) * 16 + mrow) * 256 + kg * 8;
#pragma unroll
    for (int ks = 0; ks < 8; ++ks) {
        bf16x8 a = *reinterpret_cast<const bf16x8*>(&As[mrow][ks * 32 + kg * 8]);
        bf16x8 b0 = *reinterpret_cast<const bf16x8*>(wp + 0 * 16 * 256 + ks * 32);
        bf16x8 b1f = *reinterpret_cast<const bf16x8*>(wp + 1 * 16 * 256 + ks * 32);
        bf16x8 b2 = *reinterpret_cast<const bf16x8*>(wp + 2 * 16 * 256 + ks * 32);
        bf16x8 b3 = *reinterpret_cast<const bf16x8*>(wp + 3 * 16 * 256 + ks * 32);
        acc0 = __builtin_amdgcn_mfma_f32_16x16x32_bf16(a, b0, acc0, 0, 0, 0);
        acc1 = __builtin_amdgcn_mfma_f32_16x16x32_bf16(a, b1f, acc1, 0, 0, 0);
        acc2 = __builtin_amdgcn_mfma_f32_16x16x32_bf16(a, b2, acc2, 0, 0, 0);
        acc3 = __builtin_amdgcn_mfma_f32_16x16x32_bf16(a, b3, acc3, 0, 0, 0);
    }
    f32x4 accs[4] = {acc0, acc1, acc2, acc3};
#pragma unroll
    for (int i = 0; i < 4; ++i) {
        int n = (wave * 4 + i) * 16 + mrow;
        float bb = b1[n];
#pragma unroll
        for (int r = 0; r < 4; ++r) {
            int row = kg * 4 + r;
            h16[(size_t)(n0 + row) * HIDDEN + n] = f2bf(fmaxf(accs[i][r] + bb, 0.f));
        }
    }
}

// ---------------- proj2: hWl = h@W2l (bf16 [n][64]), hWr = h@W2r + b2 (bf16 [n][48]) ----------

__global__ __launch_bounds__(256) void proj2(
    const unsigned short* __restrict__ h16, const unsigned short* __restrict__ Wpk2n,
    const float* __restrict__ b2, unsigned short* __restrict__ hWl,
    unsigned short* __restrict__ hWr) {
    __shared__ __align__(16) unsigned short As[16][AS1_STRIDE];
    int n0 = blockIdx.x * 16;
    int tid = threadIdx.x;
    int wave = tid >> 6;
    int lane = tid & 63;

#pragma unroll
    for (int itn = 0; itn < 2; ++itn) {
        int u = itn * 256 + tid;
        int row = u >> 5;
        int col = (u & 31) * 8;
        *reinterpret_cast<u16x8*>(&As[row][col]) =
            *reinterpret_cast<const u16x8*>(h16 + (size_t)(n0 + row) * HIDDEN + col);
    }
    __syncthreads();

    int mrow = lane & 15;
    int kg = lane >> 4;
    f32x4 accL = {0.f, 0.f, 0.f, 0.f};
    f32x4 accR = {0.f, 0.f, 0.f, 0.f};
    const unsigned short* wpL = Wpk2n + ((size_t)(wave * 16 + mrow)) * 256 + kg * 8;
    const unsigned short* wpR = Wpk2n + ((size_t)((wave + 4) * 16 + mrow)) * 256 + kg * 8;
#pragma unroll
    for (int ks = 0; ks < 8; ++ks) {
        bf16x8 a = *reinterpret_cast<const bf16x8*>(&As[mrow][ks * 32 + kg * 8]);
        bf16x8 bL = *reinterpret_cast<const bf16x8*>(wpL + ks * 32);
        bf16x8 bR = *reinterpret_cast<const bf16x8*>(wpR + ks * 32);
        accL = __builtin_amdgcn_mfma_f32_16x16x32_bf16(a, bL, accL, 0, 0, 0);
        accR = __builtin_amdgcn_mfma_f32_16x16x32_bf16(a, bR, accR, 0, 0, 0);
    }
    int colL = wave * 16 + mrow;
    int colR = wave * 16 + mrow;
    float bb = (colR < N_CLASSES) ? b2[colR] : 0.f;
#pragma unroll
    for (int r = 0; r < 4; ++r) {
        int row = kg * 4 + r;
        hWl[(size_t)(n0 + row) * 64 + colL] = f2bf(accL[r]);
        if (colR < 48) hWr[(size_t)(n0 + row) * 48 + colR] = f2bf(accR[r] + bb);
    }
}

// ---------------- k2b: quarter-per-node gather of hWl + hWr[dst] + log_softmax ----------------
// 256 threads, 16 nodes/block, no LDS. Quarter-wave owns node j = tid>>4; lane covers 4 cols.
// Unroll 8 = 8x8B loads in flight per lane.

__global__ __launch_bounds__(256) void k2b(
    const unsigned short* __restrict__ hWl, const unsigned short* __restrict__ hWr,
    const int* __restrict__ row_off, const int* __restrict__ csr_src,
    const float* __restrict__ inv_deg, float* __restrict__ out) {
    int n0 = blockIdx.x * 16;
    int tid = threadIdx.x;
    int j = tid >> 4;    // node 0..15
    int fl = tid & 15;   // cols fl*4 .. fl*4+3

    int n = n0 + j;
    int e0 = row_off[n], e1 = row_off[n + 1];
    int deg = e1 - e0;
    float a0 = 0.f, a1 = 0.f, a2 = 0.f, a3 = 0.f;
    int it = 0;
    for (; it + 7 < deg; it += 8) {
        int s0 = csr_src[e0 + it + 0];
        int s1 = csr_src[e0 + it + 1];
        int s2 = csr_src[e0 + it + 2];
        int s3 = csr_src[e0 + it + 3];
        int s4 = csr_src[e0 + it + 4];
        int s5 = csr_src[e0 + it + 5];
        int s6 = csr_src[e0 + it + 6];
        int s7 = csr_src[e0 + it + 7];
        ushort4 v0 = *reinterpret_cast<const ushort4*>(hWl + (size_t)s0 * 64 + fl * 4);
        ushort4 v1 = *reinterpret_cast<const ushort4*>(hWl + (size_t)s1 * 64 + fl * 4);
        ushort4 v2 = *reinterpret_cast<const ushort4*>(hWl + (size_t)s2 * 64 + fl * 4);
        ushort4 v3 = *reinterpret_cast<const ushort4*>(hWl + (size_t)s3 * 64 + fl * 4);
        ushort4 v4 = *reinterpret_cast<const ushort4*>(hWl + (size_t)s4 * 64 + fl * 4);
        ushort4 v5 = *reinterpret_cast<const ushort4*>(hWl + (size_t)s5 * 64 + fl * 4);
        ushort4 v6 = *reinterpret_cast<const ushort4*>(hWl + (size_t)s6 * 64 + fl * 4);
        ushort4 v7 = *reinterpret_cast<const ushort4*>(hWl + (size_t)s7 * 64 + fl * 4);
        a0 += ((bf2f(v0.x) + bf2f(v1.x)) + (bf2f(v2.x) + bf2f(v3.x))) +
              ((bf2f(v4.x) + bf2f(v5.x)) + (bf2f(v6.x) + bf2f(v7.x)));
        a1 += ((bf2f(v0.y) + bf2f(v1.y)) + (bf2f(v2.y) + bf2f(v3.y))) +
              ((bf2f(v4.y) + bf2f(v5.y)) + (bf2f(v6.y) + bf2f(v7.y)));
        a2 += ((bf2f(v0.z) + bf2f(v1.z)) + (bf2f(v2.z) + bf2f(v3.z))) +
              ((bf2f(v4.z) + bf2f(v5.z)) + (bf2f(v6.z) + bf2f(v7.z)));
        a3 += ((bf2f(v0.w) + bf2f(v1.w)) + (bf2f(v2.w) + bf2f(v3.w))) +
              ((bf2f(v4.w) + bf2f(v5.w)) + (bf2f(v6.w) + bf2f(v7.w)));
    }
    if (it + 3 < deg) {
        int s0 = csr_src[e0 + it + 0];
        int s1 = csr_src[e0 + it + 1];
        int s2 = csr_src[e0 + it + 2];
        int s3 = csr_src[e0 + it + 3];
        ushort4 v0 = *reinterpret_cast<const ushort4*>(hWl + (size_t)s0 * 64 + fl * 4);
        ushort4 v1 = *reinterpret_cast<const ushort4*>(hWl + (size_t)s1 * 64 + fl * 4);
        ushort4 v2 = *reinterpret_cast<const ushort4*>(hWl + (size_t)s2 * 64 + fl * 4);
        ushort4 v3 = *reinterpret_cast<const ushort4*>(hWl + (size_t)s3 * 64 + fl * 4);
        a0 += (bf2f(v0.x) + bf2f(v1.x)) + (bf2f(v2.x) + bf2f(v3.x));
        a1 += (bf2f(v0.y) + bf2f(v1.y)) + (bf2f(v2.y) + bf2f(v3.y));
        a2 += (bf2f(v0.z) + bf2f(v1.z)) + (bf2f(v2.z) + bf2f(v3.z));
        a3 += (bf2f(v0.w) + bf2f(v1.w)) + (bf2f(v2.w) + bf2f(v3.w));
        it += 4;
    }
    for (; it < deg; ++it) {
        int s = csr_src[e0 + it];
        ushort4 v = *reinterpret_cast<const ushort4*>(hWl + (size_t)s * 64 + fl * 4);
        a0 += bf2f(v.x); a1 += bf2f(v.y); a2 += bf2f(v.z); a3 += bf2f(v.w);
    }

    float v0 = 0.f, v1 = 0.f, v2 = 0.f, v3 = 0.f;
    bool valid = (fl < 10);  // cols fl*4..fl*4+3 < 40
    if (valid) {
        float id = inv_deg[n];
        ushort4 r = *reinterpret_cast<const ushort4*>(hWr + (size_t)n * 48 + fl * 4);
        v0 = a0 * id + bf2f(r.x);
        v1 = a1 * id + bf2f(r.y);
        v2 = a2 * id + bf2f(r.z);
        v3 = a3 * id + bf2f(r.w);
    }
    float m = valid ? fmaxf(fmaxf(v0, v1), fmaxf(v2, v3)) : -1e30f;
    m = fmaxf(m, __shfl_xor(m, 1));
    m = fmaxf(m, __shfl_xor(m, 2));
    m = fmaxf(m, __shfl_xor(m, 4));
    m = fmaxf(m, __shfl_xor(m, 8));
    float s = valid ? (expf(v0 - m) + expf(v1 - m)) + (expf(v2 - m) + expf(v3 - m)) : 0.f;
    s += __shfl_xor(s, 1);
    s += __shfl_xor(s, 2);
    s += __shfl_xor(s, 4);
    s += __shfl_xor(s, 8);
    float lse = m + logf(s);
    if (valid) {
        float4 o;
        o.x = v0 - lse; o.y = v1 - lse; o.z = v2 - lse; o.w = v3 - lse;
        *reinterpret_cast<float4*>(out + (size_t)n * N_CLASSES + fl * 4) = o;
    }
}

// ---------------- launch ----------------

extern "C" void kernel_launch(void* const* d_in, const int* in_sizes, int n_in,
                              void* d_out, int out_size, void* d_ws, size_t ws_size,
                              hipStream_t stream) {
    const float* x = (const float*)d_in[0];
    const int* ei = (const int*)d_in[1];  // int32 per harness contract
    const float* W1l = (const float*)d_in[2];
    const float* W1r = (const float*)d_in[3];
    const float* b1 = (const float*)d_in[4];
    const float* W2l = (const float*)d_in[5];
    const float* W2r = (const float*)d_in[6];
    const float* b2 = (const float*)d_in[7];
    float* out = (float*)d_out;

    char* p = (char*)d_ws;
    size_t off = 0;
    auto take = [&](size_t bytes) -> void* {
        void* r = p + off;
        off = (off + bytes + 255) & ~(size_t)255;
        return r;
    };
    int* counts = (int*)take(N_NODES * sizeof(int));
    int* row_off = (int*)take((N_NODES + 1) * sizeof(int));
    int* cursor = (int*)take(N_NODES * sizeof(int));
    float* invdeg = (float*)take(N_NODES * sizeof(float));
    int* csr_src = (int*)take(N_EDGES * sizeof(int));
    int* bsum = (int*)take((NCHUNK + 1) * sizeof(int));
    int* boff = (int*)take((NCHUNK + 1) * sizeof(int));
    unsigned short* h16 = (unsigned short*)take((size_t)N_NODES * HIDDEN * sizeof(unsigned short));
    unsigned short* Wpk1 = (unsigned short*)take(256 * 256 * sizeof(unsigned short));
    unsigned short* Wpk2n = (unsigned short*)take(128 * 256 * sizeof(unsigned short));
    unsigned short* x16 = (unsigned short*)take((size_t)N_NODES * F_IN * sizeof(unsigned short));
    // x16 (12.8 MB) is dead after gemm1; hWl (6.4 MB) + hWr (4.8 MB) reuse its space.
    unsigned short* hWl = x16;
    unsigned short* hWr = x16 + (size_t)N_NODES * 64;

    zero_counts<<<(N_NODES + 255) / 256, 256, 0, stream>>>(counts);
    count_kernel<<<(N_EDGES + 255) / 256, 256, 0, stream>>>(ei + N_EDGES, counts);
    scan_partials<<<NCHUNK, 256, 0, stream>>>(counts, bsum);
    scan_bsums<<<1, 256, 0, stream>>>(bsum, boff);
    scan_apply<<<NCHUNK, 256, 0, stream>>>(counts, boff, row_off, cursor, invdeg);
    fill_kernel<<<(N_EDGES + 255) / 256, 256, 0, stream>>>(ei, cursor, csr_src);
    pack_w1<<<256, 256, 0, stream>>>(W1l, W1r, Wpk1);
    pack_w2n<<<128, 256, 0, stream>>>(W2l, W2r, Wpk2n);
    conv_x16<<<(N_NODES * F_IN / 4 + 255) / 256, 256, 0, stream>>>(x, x16);
    gemm1_fused<<<N_NODES / 16, 256, 0, stream>>>(x16, row_off, csr_src, invdeg, Wpk1, b1, h16);
    proj2<<<N_NODES / 16, 256, 0, stream>>>(h16, Wpk2n, b2, hWl, hWr);
    k2b<<<N_NODES / 16, 256, 0, stream>>>(hWl, hWr, row_off, csr_src, invdeg, out);
}

// Round 15
// 225.903 us; speedup vs baseline: 1.0818x; 1.0377x over previous
//
#include <hip/hip_runtime.h>
#include <math.h>

#define N_NODES 50000
#define N_EDGES 800000
#define F_IN 128
#define HIDDEN 256
#define N_CLASSES 40

#define CHUNK 256
#define NCHUNK ((N_NODES + CHUNK - 1) / CHUNK)  // 196
#define IDXCAP 1024

typedef __attribute__((ext_vector_type(8))) short bf16x8;
typedef __attribute__((ext_vector_type(4))) float f32x4;
typedef __attribute__((ext_vector_type(8))) unsigned short u16x8;

// ---------------- bf16 helpers ----------------

__device__ __forceinline__ float bf2f(unsigned short u) {
    unsigned int t = ((unsigned int)u) << 16;
    float f;
    __builtin_memcpy(&f, &t, 4);
    return f;
}

__device__ __forceinline__ unsigned short f2bf(float f) {
    unsigned int t;
    __builtin_memcpy(&t, &f, 4);
    unsigned int r = (t + 0x7fffu + ((t >> 16) & 1u)) >> 16;  // RNE
    return (unsigned short)r;
}

// ---------------- CSR build ----------------

__global__ void zero_counts(int* __restrict__ counts) {
    int i = blockIdx.x * blockDim.x + threadIdx.x;
    if (i < N_NODES) counts[i] = 0;
}

// edge_index arrives as int32 (JAX x64-disabled downgrades int64)
__global__ void count_kernel(const int* __restrict__ dst, int* __restrict__ counts) {
    int e = blockIdx.x * blockDim.x + threadIdx.x;
    if (e < N_EDGES) {
        int d = dst[e];
        d = (d < 0) ? 0 : (d >= N_NODES ? N_NODES - 1 : d);
        atomicAdd(&counts[d], 1);
    }
}

__global__ __launch_bounds__(256) void scan_partials(const int* __restrict__ counts,
                                                     int* __restrict__ bsum) {
    __shared__ int red[4];
    int b = blockIdx.x;
    int i = b * CHUNK + threadIdx.x;
    int v = (i < N_NODES) ? counts[i] : 0;
    for (int off = 32; off > 0; off >>= 1) v += __shfl_down(v, off, 64);
    int wave = threadIdx.x >> 6;
    int lane = threadIdx.x & 63;
    if (lane == 0) red[wave] = v;
    __syncthreads();
    if (threadIdx.x == 0) bsum[b] = red[0] + red[1] + red[2] + red[3];
}

// fused: per-block exclusive offset (reduce of bsum[0..b-1]) + in-chunk scan + emit
__global__ __launch_bounds__(256) void scan_apply2(const int* __restrict__ counts,
                                                   const int* __restrict__ bsum,
                                                   int* __restrict__ row_off,
                                                   int* __restrict__ cursor,
                                                   float* __restrict__ inv_deg) {
    __shared__ int s[256];
    __shared__ int red[4];
    int b = blockIdx.x;
    int tid = threadIdx.x;
    // block offset: sum of bsum[i] for i < b (NCHUNK = 196 < 256)
    int r = (tid < b && tid < NCHUNK) ? bsum[tid] : 0;
    for (int off = 32; off > 0; off >>= 1) r += __shfl_down(r, off, 64);
    if ((tid & 63) == 0) red[tid >> 6] = r;
    int i = b * CHUNK + tid;
    int v = (i < N_NODES) ? counts[i] : 0;
    s[tid] = v;
    __syncthreads();
    int boff_b = red[0] + red[1] + red[2] + red[3];
    for (int off = 1; off < 256; off <<= 1) {
        int t = (tid >= off) ? s[tid - off] : 0;
        __syncthreads();
        s[tid] += t;
        __syncthreads();
    }
    if (i < N_NODES) {
        int excl = boff_b + s[tid] - v;
        row_off[i] = excl;
        cursor[i] = excl;
        inv_deg[i] = 1.0f / fmaxf((float)v, 1.0f);
        if (i == N_NODES - 1) row_off[N_NODES] = excl + v;
    }
}

__global__ void fill_kernel(const int* __restrict__ ei, int* __restrict__ cursor,
                            int* __restrict__ csr_src) {
    int e = blockIdx.x * blockDim.x + threadIdx.x;
    if (e < N_EDGES) {
        int s = ei[e];
        int d = ei[N_EDGES + e];
        s = (s < 0) ? 0 : (s >= N_NODES ? N_NODES - 1 : s);
        d = (d < 0) ? 0 : (d >= N_NODES ? N_NODES - 1 : d);
        int pos = atomicAdd(&cursor[d], 1);
        if (pos >= 0 && pos < N_EDGES) csr_src[pos] = s;
    }
}

// ---------------- x -> bf16 conversion ----------------

__global__ void conv_x16(const float* __restrict__ x, unsigned short* __restrict__ x16) {
    int i = blockIdx.x * blockDim.x + threadIdx.x;  // 4 elems/thread
    if (i < N_NODES * F_IN / 4) {
        float4 v = reinterpret_cast<const float4*>(x)[i];
        ushort4 o;
        o.x = f2bf(v.x); o.y = f2bf(v.y); o.z = f2bf(v.z); o.w = f2bf(v.w);
        reinterpret_cast<ushort4*>(x16)[i] = o;
    }
}

// ---------------- weight packs ----------------

__global__ void pack_w1(const float* __restrict__ W1l, const float* __restrict__ W1r,
                        unsigned short* __restrict__ Wpk) {
    int n = blockIdx.x;
    int k = threadIdx.x;
    float v = (k < F_IN) ? W1l[(size_t)k * HIDDEN + n] : W1r[(size_t)(k - F_IN) * HIDDEN + n];
    Wpk[(size_t)n * 256 + k] = f2bf(v);
}

// Wpk2n[n][k] bf16, n in [0,128): n<64 -> W2l col n (0 if n>=40); n>=64 -> W2r col n-64 (0 if >=40)
__global__ void pack_w2n(const float* __restrict__ W2l, const float* __restrict__ W2r,
                         unsigned short* __restrict__ Wpk2n) {
    int n = blockIdx.x;   // 0..127
    int k = threadIdx.x;  // 0..255
    float v = 0.f;
    if (n < 64) {
        if (n < N_CLASSES) v = W2l[(size_t)k * N_CLASSES + n];
    } else {
        int m = n - 64;
        if (m < N_CLASSES) v = W2r[(size_t)k * N_CLASSES + m];
    }
    Wpk2n[(size_t)n * 256 + k] = f2bf(v);
}

// ---------------- layer1_fused: gather + GEMM1+relu + proj2, h never leaves LDS ----------
// 256 threads (4 waves), 16 nodes/block. Block's edge indices staged into LDS first
// (coalesced); quarter-wave owns one node; unroll 8 = 8x16B row loads in flight/lane.
// Phase2: MFMA [mean|x]@Wpk1 -> h (acc). Phase3: relu+bf16 -> Hs (LDS).
// Phase4: MFMA h@Wpk2n -> hWl [n][64], hWr [n][48] (+b2).

#define AS1_STRIDE 264

__global__ __launch_bounds__(256) void layer1_fused(
    const unsigned short* __restrict__ x16, const int* __restrict__ row_off,
    const int* __restrict__ csr_src, const float* __restrict__ inv_deg,
    const unsigned short* __restrict__ Wpk, const float* __restrict__ b1,
    const unsigned short* __restrict__ Wpk2n, const float* __restrict__ b2,
    unsigned short* __restrict__ hWl, unsigned short* __restrict__ hWr) {
    __shared__ __align__(16) unsigned short As[16][AS1_STRIDE];
    __shared__ __align__(16) unsigned short Hs[16][AS1_STRIDE];
    __shared__ int eidx[IDXCAP];
    __shared__ int s_roff[17];
    int n0 = blockIdx.x * 16;
    int tid = threadIdx.x;
    int wave = tid >> 6;
    int lane = tid & 63;

    // ---- stage row offsets + edge indices (coalesced) ----
    int eb0 = row_off[n0];
    int eb1 = row_off[n0 + 16];
    if (tid < 17) s_roff[tid] = row_off[n0 + tid];
    int cnt = eb1 - eb0;
    int staged = cnt < IDXCAP ? cnt : IDXCAP;
    for (int t = tid; t < staged; t += 256) eidx[t] = csr_src[eb0 + t];
    __syncthreads();

    // ---- phase 1: gather, quarter-per-node ----
    int j = tid >> 4;    // node 0..15
    int fl = tid & 15;   // 8 bf16 at fl*8
    {
        int n = n0 + j;
        int e0 = s_roff[j], e1 = s_roff[j + 1];
        int deg = e1 - e0;
        // index source: LDS if this node's whole range staged, else global (rare)
        const int* ip;
        int ib;
        if (e1 - eb0 <= staged) { ip = eidx; ib = e0 - eb0; }
        else                    { ip = csr_src; ib = e0; }
        float a[8] = {0.f, 0.f, 0.f, 0.f, 0.f, 0.f, 0.f, 0.f};
        int it = 0;
        for (; it + 7 < deg; it += 8) {
            int s0 = ip[ib + it + 0];
            int s1 = ip[ib + it + 1];
            int s2 = ip[ib + it + 2];
            int s3 = ip[ib + it + 3];
            int s4 = ip[ib + it + 4];
            int s5 = ip[ib + it + 5];
            int s6 = ip[ib + it + 6];
            int s7 = ip[ib + it + 7];
            u16x8 v0 = *reinterpret_cast<const u16x8*>(x16 + (size_t)s0 * F_IN + fl * 8);
            u16x8 v1 = *reinterpret_cast<const u16x8*>(x16 + (size_t)s1 * F_IN + fl * 8);
            u16x8 v2 = *reinterpret_cast<const u16x8*>(x16 + (size_t)s2 * F_IN + fl * 8);
            u16x8 v3 = *reinterpret_cast<const u16x8*>(x16 + (size_t)s3 * F_IN + fl * 8);
            u16x8 v4 = *reinterpret_cast<const u16x8*>(x16 + (size_t)s4 * F_IN + fl * 8);
            u16x8 v5 = *reinterpret_cast<const u16x8*>(x16 + (size_t)s5 * F_IN + fl * 8);
            u16x8 v6 = *reinterpret_cast<const u16x8*>(x16 + (size_t)s6 * F_IN + fl * 8);
            u16x8 v7 = *reinterpret_cast<const u16x8*>(x16 + (size_t)s7 * F_IN + fl * 8);
#pragma unroll
            for (int i = 0; i < 8; ++i)
                a[i] += ((bf2f(v0[i]) + bf2f(v1[i])) + (bf2f(v2[i]) + bf2f(v3[i]))) +
                        ((bf2f(v4[i]) + bf2f(v5[i])) + (bf2f(v6[i]) + bf2f(v7[i])));
        }
        if (it + 3 < deg) {
            int s0 = ip[ib + it + 0];
            int s1 = ip[ib + it + 1];
            int s2 = ip[ib + it + 2];
            int s3 = ip[ib + it + 3];
            u16x8 v0 = *reinterpret_cast<const u16x8*>(x16 + (size_t)s0 * F_IN + fl * 8);
            u16x8 v1 = *reinterpret_cast<const u16x8*>(x16 + (size_t)s1 * F_IN + fl * 8);
            u16x8 v2 = *reinterpret_cast<const u16x8*>(x16 + (size_t)s2 * F_IN + fl * 8);
            u16x8 v3 = *reinterpret_cast<const u16x8*>(x16 + (size_t)s3 * F_IN + fl * 8);
#pragma unroll
            for (int i = 0; i < 8; ++i)
                a[i] += (bf2f(v0[i]) + bf2f(v1[i])) + (bf2f(v2[i]) + bf2f(v3[i]));
            it += 4;
        }
        for (; it < deg; ++it) {
            int s = ip[ib + it];
            u16x8 v = *reinterpret_cast<const u16x8*>(x16 + (size_t)s * F_IN + fl * 8);
#pragma unroll
            for (int i = 0; i < 8; ++i) a[i] += bf2f(v[i]);
        }
        float id = inv_deg[n];
        u16x8 m;
#pragma unroll
        for (int i = 0; i < 8; ++i) m[i] = f2bf(a[i] * id);
        *reinterpret_cast<u16x8*>(&As[j][fl * 8]) = m;
        *reinterpret_cast<u16x8*>(&As[j][F_IN + fl * 8]) =
            *reinterpret_cast<const u16x8*>(x16 + (size_t)n * F_IN + fl * 8);
    }
    __syncthreads();

    // ---- phase 2: MFMA [mean|x]@Wpk1 (m89-verified layout) ----
    int mrow = lane & 15;
    int kg = lane >> 4;
    f32x4 acc0 = {0.f, 0.f, 0.f, 0.f};
    f32x4 acc1 = {0.f, 0.f, 0.f, 0.f};
    f32x4 acc2 = {0.f, 0.f, 0.f, 0.f};
    f32x4 acc3 = {0.f, 0.f, 0.f, 0.f};
    const unsigned short* wp = Wpk + ((size_t)(wave * 4) * 16 + mrow) * 256 + kg * 8;
#pragma unroll
    for (int ks = 0; ks < 8; ++ks) {
        bf16x8 a = *reinterpret_cast<const bf16x8*>(&As[mrow][ks * 32 + kg * 8]);
        bf16x8 b0 = *reinterpret_cast<const bf16x8*>(wp + 0 * 16 * 256 + ks * 32);
        bf16x8 b1f = *reinterpret_cast<const bf16x8*>(wp + 1 * 16 * 256 + ks * 32);
        bf16x8 b2f = *reinterpret_cast<const bf16x8*>(wp + 2 * 16 * 256 + ks * 32);
        bf16x8 b3f = *reinterpret_cast<const bf16x8*>(wp + 3 * 16 * 256 + ks * 32);
        acc0 = __builtin_amdgcn_mfma_f32_16x16x32_bf16(a, b0, acc0, 0, 0, 0);
        acc1 = __builtin_amdgcn_mfma_f32_16x16x32_bf16(a, b1f, acc1, 0, 0, 0);
        acc2 = __builtin_amdgcn_mfma_f32_16x16x32_bf16(a, b2f, acc2, 0, 0, 0);
        acc3 = __builtin_amdgcn_mfma_f32_16x16x32_bf16(a, b3f, acc3, 0, 0, 0);
    }
    // ---- phase 3: h = relu(acc + b1), bf16, into LDS (never to HBM) ----
    {
        f32x4 accs[4] = {acc0, acc1, acc2, acc3};
#pragma unroll
        for (int i = 0; i < 4; ++i) {
            int n = (wave * 4 + i) * 16 + mrow;
            float bb = b1[n];
#pragma unroll
            for (int r = 0; r < 4; ++r) {
                int row = kg * 4 + r;
                Hs[row][n] = f2bf(fmaxf(accs[i][r] + bb, 0.f));
            }
        }
    }
    __syncthreads();

    // ---- phase 4: proj2 -- hWl = h@W2l, hWr = h@W2r + b2 ----
    f32x4 accL = {0.f, 0.f, 0.f, 0.f};
    f32x4 accR = {0.f, 0.f, 0.f, 0.f};
    const unsigned short* wpL = Wpk2n + ((size_t)(wave * 16 + mrow)) * 256 + kg * 8;
    const unsigned short* wpR = Wpk2n + ((size_t)((wave + 4) * 16 + mrow)) * 256 + kg * 8;
#pragma unroll
    for (int ks = 0; ks < 8; ++ks) {
        bf16x8 a = *reinterpret_cast<const bf16x8*>(&Hs[mrow][ks * 32 + kg * 8]);
        bf16x8 bL = *reinterpret_cast<const bf16x8*>(wpL + ks * 32);
        bf16x8 bR = *reinterpret_cast<const bf16x8*>(wpR + ks * 32);
        accL = __builtin_amdgcn_mfma_f32_16x16x32_bf16(a, bL, accL, 0, 0, 0);
        accR = __builtin_amdgcn_mfma_f32_16x16x32_bf16(a, bR, accR, 0, 0, 0);
    }
    int col = wave * 16 + mrow;
    float bb2 = (col < N_CLASSES) ? b2[col] : 0.f;
#pragma unroll
    for (int r = 0; r < 4; ++r) {
        int row = kg * 4 + r;
        hWl[(size_t)(n0 + row) * 64 + col] = f2bf(accL[r]);
        if (col < 48) hWr[(size_t)(n0 + row) * 48 + col] = f2bf(accR[r] + bb2);
    }
}

// ---------------- k2b: LDS-staged idx + quarter-per-node gather + log_softmax ----------

__global__ __launch_bounds__(256) void k2b(
    const unsigned short* __restrict__ hWl, const unsigned short* __restrict__ hWr,
    const int* __restrict__ row_off, const int* __restrict__ csr_src,
    const float* __restrict__ inv_deg, float* __restrict__ out) {
    __shared__ int eidx[IDXCAP];
    __shared__ int s_roff[17];
    int n0 = blockIdx.x * 16;
    int tid = threadIdx.x;

    int eb0 = row_off[n0];
    int eb1 = row_off[n0 + 16];
    if (tid < 17) s_roff[tid] = row_off[n0 + tid];
    int cnt = eb1 - eb0;
    int staged = cnt < IDXCAP ? cnt : IDXCAP;
    for (int t = tid; t < staged; t += 256) eidx[t] = csr_src[eb0 + t];
    __syncthreads();

    int j = tid >> 4;    // node 0..15
    int fl = tid & 15;   // cols fl*4 .. fl*4+3

    int n = n0 + j;
    int e0 = s_roff[j], e1 = s_roff[j + 1];
    int deg = e1 - e0;
    const int* ip;
    int ib;
    if (e1 - eb0 <= staged) { ip = eidx; ib = e0 - eb0; }
    else                    { ip = csr_src; ib = e0; }
    float a0 = 0.f, a1 = 0.f, a2 = 0.f, a3 = 0.f;
    int it = 0;
    for (; it + 7 < deg; it += 8) {
        int s0 = ip[ib + it + 0];
        int s1 = ip[ib + it + 1];
        int s2 = ip[ib + it + 2];
        int s3 = ip[ib + it + 3];
        int s4 = ip[ib + it + 4];
        int s5 = ip[ib + it + 5];
        int s6 = ip[ib + it + 6];
        int s7 = ip[ib + it + 7];
        ushort4 v0 = *reinterpret_cast<const ushort4*>(hWl + (size_t)s0 * 64 + fl * 4);
        ushort4 v1 = *reinterpret_cast<const ushort4*>(hWl + (size_t)s1 * 64 + fl * 4);
        ushort4 v2 = *reinterpret_cast<const ushort4*>(hWl + (size_t)s2 * 64 + fl * 4);
        ushort4 v3 = *reinterpret_cast<const ushort4*>(hWl + (size_t)s3 * 64 + fl * 4);
        ushort4 v4 = *reinterpret_cast<const ushort4*>(hWl + (size_t)s4 * 64 + fl * 4);
        ushort4 v5 = *reinterpret_cast<const ushort4*>(hWl + (size_t)s5 * 64 + fl * 4);
        ushort4 v6 = *reinterpret_cast<const ushort4*>(hWl + (size_t)s6 * 64 + fl * 4);
        ushort4 v7 = *reinterpret_cast<const ushort4*>(hWl + (size_t)s7 * 64 + fl * 4);
        a0 += ((bf2f(v0.x) + bf2f(v1.x)) + (bf2f(v2.x) + bf2f(v3.x))) +
              ((bf2f(v4.x) + bf2f(v5.x)) + (bf2f(v6.x) + bf2f(v7.x)));
        a1 += ((bf2f(v0.y) + bf2f(v1.y)) + (bf2f(v2.y) + bf2f(v3.y))) +
              ((bf2f(v4.y) + bf2f(v5.y)) + (bf2f(v6.y) + bf2f(v7.y)));
        a2 += ((bf2f(v0.z) + bf2f(v1.z)) + (bf2f(v2.z) + bf2f(v3.z))) +
              ((bf2f(v4.z) + bf2f(v5.z)) + (bf2f(v6.z) + bf2f(v7.z)));
        a3 += ((bf2f(v0.w) + bf2f(v1.w)) + (bf2f(v2.w) + bf2f(v3.w))) +
              ((bf2f(v4.w) + bf2f(v5.w)) + (bf2f(v6.w) + bf2f(v7.w)));
    }
    if (it + 3 < deg) {
        int s0 = ip[ib + it + 0];
        int s1 = ip[ib + it + 1];
        int s2 = ip[ib + it + 2];
        int s3 = ip[ib + it + 3];
        ushort4 v0 = *reinterpret_cast<const ushort4*>(hWl + (size_t)s0 * 64 + fl * 4);
        ushort4 v1 = *reinterpret_cast<const ushort4*>(hWl + (size_t)s1 * 64 + fl * 4);
        ushort4 v2 = *reinterpret_cast<const ushort4*>(hWl + (size_t)s2 * 64 + fl * 4);
        ushort4 v3 = *reinterpret_cast<const ushort4*>(hWl + (size_t)s3 * 64 + fl * 4);
        a0 += (bf2f(v0.x) + bf2f(v1.x)) + (bf2f(v2.x) + bf2f(v3.x));
        a1 += (bf2f(v0.y) + bf2f(v1.y)) + (bf2f(v2.y) + bf2f(v3.y));
        a2 += (bf2f(v0.z) + bf2f(v1.z)) + (bf2f(v2.z) + bf2f(v3.z));
        a3 += (bf2f(v0.w) + bf2f(v1.w)) + (bf2f(v2.w) + bf2f(v3.w));
        it += 4;
    }
    for (; it < deg; ++it) {
        int s = ip[ib + it];
        ushort4 v = *reinterpret_cast<const ushort4*>(hWl + (size_t)s * 64 + fl * 4);
        a0 += bf2f(v.x); a1 += bf2f(v.y); a2 += bf2f(v.z); a3 += bf2f(v.w);
    }

    float v0 = 0.f, v1 = 0.f, v2 = 0.f, v3 = 0.f;
    bool valid = (fl < 10);  // cols fl*4..fl*4+3 < 40
    if (valid) {
        float id = inv_deg[n];
        ushort4 r = *reinterpret_cast<const ushort4*>(hWr + (size_t)n * 48 + fl * 4);
        v0 = a0 * id + bf2f(r.x);
        v1 = a1 * id + bf2f(r.y);
        v2 = a2 * id + bf2f(r.z);
        v3 = a3 * id + bf2f(r.w);
    }
    float m = valid ? fmaxf(fmaxf(v0, v1), fmaxf(v2, v3)) : -1e30f;
    m = fmaxf(m, __shfl_xor(m, 1));
    m = fmaxf(m, __shfl_xor(m, 2));
    m = fmaxf(m, __shfl_xor(m, 4));
    m = fmaxf(m, __shfl_xor(m, 8));
    float s = valid ? (expf(v0 - m) + expf(v1 - m)) + (expf(v2 - m) + expf(v3 - m)) : 0.f;
    s += __shfl_xor(s, 1);
    s += __shfl_xor(s, 2);
    s += __shfl_xor(s, 4);
    s += __shfl_xor(s, 8);
    float lse = m + logf(s);
    if (valid) {
        float4 o;
        o.x = v0 - lse; o.y = v1 - lse; o.z = v2 - lse; o.w = v3 - lse;
        *reinterpret_cast<float4*>(out + (size_t)n * N_CLASSES + fl * 4) = o;
    }
}

// ---------------- launch ----------------

extern "C" void kernel_launch(void* const* d_in, const int* in_sizes, int n_in,
                              void* d_out, int out_size, void* d_ws, size_t ws_size,
                              hipStream_t stream) {
    const float* x = (const float*)d_in[0];
    const int* ei = (const int*)d_in[1];  // int32 per harness contract
    const float* W1l = (const float*)d_in[2];
    const float* W1r = (const float*)d_in[3];
    const float* b1 = (const float*)d_in[4];
    const float* W2l = (const float*)d_in[5];
    const float* W2r = (const float*)d_in[6];
    const float* b2 = (const float*)d_in[7];
    float* out = (float*)d_out;

    char* p = (char*)d_ws;
    size_t off = 0;
    auto take = [&](size_t bytes) -> void* {
        void* r = p + off;
        off = (off + bytes + 255) & ~(size_t)255;
        return r;
    };
    int* counts = (int*)take(N_NODES * sizeof(int));
    int* row_off = (int*)take((N_NODES + 1) * sizeof(int));
    int* cursor = (int*)take(N_NODES * sizeof(int));
    float* invdeg = (float*)take(N_NODES * sizeof(float));
    int* csr_src = (int*)take(N_EDGES * sizeof(int));
    int* bsum = (int*)take((NCHUNK + 1) * sizeof(int));
    unsigned short* Wpk1 = (unsigned short*)take(256 * 256 * sizeof(unsigned short));
    unsigned short* Wpk2n = (unsigned short*)take(128 * 256 * sizeof(unsigned short));
    unsigned short* x16 = (unsigned short*)take((size_t)N_NODES * F_IN * sizeof(unsigned short));
    unsigned short* hWl = (unsigned short*)take((size_t)N_NODES * 64 * sizeof(unsigned short));
    unsigned short* hWr = (unsigned short*)take((size_t)N_NODES * 48 * sizeof(unsigned short));
    // total ~= 42 MB (h16 eliminated; within proven budget)

    zero_counts<<<(N_NODES + 255) / 256, 256, 0, stream>>>(counts);
    count_kernel<<<(N_EDGES + 255) / 256, 256, 0, stream>>>(ei + N_EDGES, counts);
    scan_partials<<<NCHUNK, 256, 0, stream>>>(counts, bsum);
    scan_apply2<<<NCHUNK, 256, 0, stream>>>(counts, bsum, row_off, cursor, invdeg);
    fill_kernel<<<(N_EDGES + 255) / 256, 256, 0, stream>>>(ei, cursor, csr_src);
    pack_w1<<<256, 256, 0, stream>>>(W1l, W1r, Wpk1);
    pack_w2n<<<128, 256, 0, stream>>>(W2l, W2r, Wpk2n);
    conv_x16<<<(N_NODES * F_IN / 4 + 255) / 256, 256, 0, stream>>>(x, x16);
    layer1_fused<<<N_NODES / 16, 256, 0, stream>>>(x16, row_off, csr_src, invdeg, Wpk1, b1,
                                                   Wpk2n, b2, hWl, hWr);
    k2b<<<N_NODES / 16, 256, 0, stream>>>(hWl, hWr, row_off, csr_src, invdeg, out);
}